// Round 1
// baseline (818.761 us; speedup 1.0000x reference)
//
#include <hip/hip_runtime.h>
#include <math.h>

// Problem constants (fixed by the reference setup_inputs)
#define B_DIM 131072
#define F_DIM 512
#define K_DIM 31      // num knots
#define S_DIM 32      // num splines = K+1
#define EPSV  1e-3f

// Main kernel tiling
#define TF        128                      // features per block
#define THREADS   256
#define GRID_X    (F_DIM / TF)             // 4
#define GRID_Y    512
#define ROWS_PER_Y   (B_DIM / GRID_Y)      // 256 rows per block
#define SEGS         (TF / 4)              // 32 threads cover one row-segment
#define ROWS_PER_PASS (THREADS / SEGS)     // 8 rows per pass
#define ITERS        (ROWS_PER_Y / ROWS_PER_PASS)  // 32

// ---------------------------------------------------------------------------
// Setup: per-feature sort + softplus + cumsum -> line table (slope, intercept)
// 8 features per 256-thread block; thread = (feature_in_block, knot k).
// ---------------------------------------------------------------------------
__global__ __launch_bounds__(256) void plas_setup_kernel(
    const float* __restrict__ x_pos,   // [F, K]
    const float* __restrict__ slope,   // [F, S]
    const float* __restrict__ y_bias,  // [F]
    float*  __restrict__ g_xs,         // [F, K]  sorted knots
    float2* __restrict__ g_line)       // [F, S]  (slope_c, intercept)
{
    __shared__ float v[8][K_DIM];
    __shared__ float xs_s[8][K_DIM];
    __shared__ float sc[8][S_DIM];
    __shared__ float yp[8][K_DIM];

    const int tid = threadIdx.x;
    const int fb  = tid >> 5;        // 0..7 feature in block
    const int k   = tid & 31;        // 0..31
    const int f   = blockIdx.x * 8 + fb;

    // softplus(slope) + EPS  (stable: max(x,0) + log1p(exp(-|x|)))
    {
        float s = slope[f * S_DIM + k];
        sc[fb][k] = fmaxf(s, 0.0f) + log1pf(expf(-fabsf(s))) + EPSV;
    }
    if (k < K_DIM) v[fb][k] = x_pos[f * K_DIM + k];
    __syncthreads();

    // rank-based sort (O(K^2) parallel over knots; ties broken by index)
    if (k < K_DIM) {
        float val = v[fb][k];
        int rank = 0;
        #pragma unroll
        for (int j = 0; j < K_DIM; ++j) {
            float o = v[fb][j];
            rank += (o < val) || (o == val && j < k);
        }
        xs_s[fb][rank] = val;
    }
    __syncthreads();

    // sequential cumsum (one leader thread per feature; only 31 steps)
    if (k == 0) {
        float y = xs_s[fb][0] + y_bias[f];
        yp[fb][0] = y;
        #pragma unroll
        for (int m = 1; m < K_DIM; ++m) {
            y += (xs_s[fb][m] - xs_s[fb][m - 1]) * sc[fb][m];
            yp[fb][m] = y;
        }
    }
    __syncthreads();

    // line table: for search result idx (0..31), x_idx = max(idx-1,0)
    // out = y_pos[x_idx] + (x - xs[x_idx]) * slope_c[idx] = intercept + x*slope
    {
        int xk = (k > 0) ? (k - 1) : 0;         // <= 30
        float so = sc[fb][k];
        float2 lb;
        lb.x = so;
        lb.y = yp[fb][xk] - xs_s[fb][xk] * so;
        g_line[f * S_DIM + k] = lb;
        if (k < K_DIM) g_xs[f * K_DIM + k] = xs_s[fb][k];
    }
}

// ---------------------------------------------------------------------------
// Main streaming pass. Block = 128 features x 256 rows-strip.
// Tables staged in LDS with XOR swizzle: slot = key ^ (f_local>>2).
// Since thread t handles features 4t..4t+3, (f_local>>2) == lane id -> the
// swizzle spreads data-dependent search reads across all 32 banks.
// ---------------------------------------------------------------------------
__global__ __launch_bounds__(THREADS) void plas_main_kernel(
    const float*  __restrict__ inp,    // [B, F]
    const float*  __restrict__ g_xs,   // [F, K]
    const float2* __restrict__ g_line, // [F, S]
    float* __restrict__ out,           // [B, F]
    float* __restrict__ ssel)          // [B, F]
{
    __shared__ float  lxs[TF * 32];    // swizzled: [f][k ^ swz(f)]
    __shared__ float2 lline[TF * 32];  // swizzled: [f][idx ^ swz(f)]

    const int tid = threadIdx.x;
    const int f0  = blockIdx.x * TF;

    // stage tables: 16 passes x (8 features x 32 slots)
    {
        const int fl_base = tid >> 5;      // 0..7
        const int kk      = tid & 31;
        #pragma unroll
        for (int pass = 0; pass < TF / 8; ++pass) {
            const int fl  = pass * 8 + fl_base;
            const int swz = (fl >> 2) & 31;
            lline[fl * 32 + (kk ^ swz)] = g_line[(size_t)(f0 + fl) * S_DIM + kk];
            if (kk < K_DIM)
                lxs[fl * 32 + (kk ^ swz)] = g_xs[(size_t)(f0 + fl) * K_DIM + kk];
        }
    }
    __syncthreads();

    const int t4   = tid & 31;     // row-segment id == swizzle key
    const int trow = tid >> 5;     // 0..7
    const int fbse = t4 * 4;       // local feature base (4 consecutive features)
    const int swz  = t4;           // (f_local>>2) for all 4 features

    const float*  xsb = &lxs[fbse * 32];
    const float2* lnb = &lline[fbse * 32];

    size_t b = (size_t)blockIdx.y * ROWS_PER_Y + trow;

    for (int it = 0; it < ITERS; ++it) {
        const size_t base = b * F_DIM + f0 + fbse;
        const float4 x4 = *reinterpret_cast<const float4*>(inp + base);
        const float xv[4] = {x4.x, x4.y, x4.z, x4.w};
        float ov[4], sv[4];

        #pragma unroll
        for (int j = 0; j < 4; ++j) {
            const float* xs = xsb + j * 32;
            const float x = xv[j];
            // branchless upper_bound over 31 sorted knots (count of xs[k] <= x)
            int idx;
            idx  = (xs[15 ^ swz]        <= x) ? 16 : 0;
            idx += (xs[(idx + 7) ^ swz] <= x) ? 8 : 0;
            idx += (xs[(idx + 3) ^ swz] <= x) ? 4 : 0;
            idx += (xs[(idx + 1) ^ swz] <= x) ? 2 : 0;
            idx += (xs[idx ^ swz]       <= x) ? 1 : 0;
            const float2 lb = lnb[j * 32 + (idx ^ swz)];
            sv[j] = lb.x;
            ov[j] = fmaf(x, lb.x, lb.y);
        }

        *reinterpret_cast<float4*>(out  + base) = make_float4(ov[0], ov[1], ov[2], ov[3]);
        *reinterpret_cast<float4*>(ssel + base) = make_float4(sv[0], sv[1], sv[2], sv[3]);
        b += ROWS_PER_PASS;
    }
}

extern "C" void kernel_launch(void* const* d_in, const int* in_sizes, int n_in,
                              void* d_out, int out_size, void* d_ws, size_t ws_size,
                              hipStream_t stream) {
    const float* inputs = (const float*)d_in[0];   // [B, F]
    const float* x_pos  = (const float*)d_in[1];   // [F, K]
    const float* slope  = (const float*)d_in[2];   // [F, S]
    const float* y_bias = (const float*)d_in[3];   // [F, 1]

    float* out  = (float*)d_out;                   // outputs [B,F]
    float* ssel = (float*)d_out + (size_t)B_DIM * F_DIM;  // slope_sel [B,F]

    // workspace layout: line table first (8B aligned), then sorted knots
    float2* g_line = (float2*)d_ws;                         // F*S float2 = 128 KiB
    float*  g_xs   = (float*)d_ws + (size_t)F_DIM * S_DIM * 2;  // F*K floats

    plas_setup_kernel<<<F_DIM / 8, 256, 0, stream>>>(x_pos, slope, y_bias, g_xs, g_line);

    dim3 grid(GRID_X, GRID_Y);
    plas_main_kernel<<<grid, THREADS, 0, stream>>>(inputs, g_xs, g_line, out, ssel);
}

// Round 2
// 717.966 us; speedup vs baseline: 1.1404x; 1.1404x over previous
//
#include <hip/hip_runtime.h>
#include <math.h>

// Problem constants (fixed by the reference setup_inputs)
#define B_DIM 131072
#define F_DIM 512
#define K_DIM 31      // num knots
#define S_DIM 32      // num splines = K+1
#define EPSV  1e-3f

// Main kernel tiling
#define TF        64                       // features per block (24 KB LDS -> 6 blocks/CU)
#define THREADS   256
#define GRID_X    (F_DIM / TF)             // 8
#define GRID_Y    512
#define ROWS_PER_Y   (B_DIM / GRID_Y)      // 256 rows per block
#define SEGS         (TF / 4)              // 16 threads cover one row-segment
#define ROWS_PER_PASS (THREADS / SEGS)     // 16 rows per pass
#define ITERS        (ROWS_PER_Y / ROWS_PER_PASS)  // 16

typedef float f4 __attribute__((ext_vector_type(4)));
typedef float f2 __attribute__((ext_vector_type(2)));

// ---------------------------------------------------------------------------
// Setup: per-feature sort + softplus + cumsum -> line table (slope, intercept)
// 8 features per 256-thread block; thread = (feature_in_block, knot k).
// ---------------------------------------------------------------------------
__global__ __launch_bounds__(256) void plas_setup_kernel(
    const float* __restrict__ x_pos,   // [F, K]
    const float* __restrict__ slope,   // [F, S]
    const float* __restrict__ y_bias,  // [F]
    float*  __restrict__ g_xs,         // [F, K]  sorted knots
    float2* __restrict__ g_line)       // [F, S]  (slope_c, intercept)
{
    __shared__ float v[8][K_DIM];
    __shared__ float xs_s[8][K_DIM];
    __shared__ float sc[8][S_DIM];
    __shared__ float yp[8][K_DIM];

    const int tid = threadIdx.x;
    const int fb  = tid >> 5;        // 0..7 feature in block
    const int k   = tid & 31;        // 0..31
    const int f   = blockIdx.x * 8 + fb;

    // softplus(slope) + EPS  (stable: max(x,0) + log1p(exp(-|x|)))
    {
        float s = slope[f * S_DIM + k];
        sc[fb][k] = fmaxf(s, 0.0f) + log1pf(expf(-fabsf(s))) + EPSV;
    }
    if (k < K_DIM) v[fb][k] = x_pos[f * K_DIM + k];
    __syncthreads();

    // rank-based sort (O(K^2) parallel over knots; ties broken by index)
    if (k < K_DIM) {
        float val = v[fb][k];
        int rank = 0;
        #pragma unroll
        for (int j = 0; j < K_DIM; ++j) {
            float o = v[fb][j];
            rank += (o < val) || (o == val && j < k);
        }
        xs_s[fb][rank] = val;
    }
    __syncthreads();

    // sequential cumsum (one leader thread per feature; only 31 steps)
    if (k == 0) {
        float y = xs_s[fb][0] + y_bias[f];
        yp[fb][0] = y;
        #pragma unroll
        for (int m = 1; m < K_DIM; ++m) {
            y += (xs_s[fb][m] - xs_s[fb][m - 1]) * sc[fb][m];
            yp[fb][m] = y;
        }
    }
    __syncthreads();

    // line table: for search result idx (0..31), x_idx = max(idx-1,0)
    // out = y_pos[x_idx] + (x - xs[x_idx]) * slope_c[idx] = intercept + x*slope
    {
        int xk = (k > 0) ? (k - 1) : 0;         // <= 30
        float so = sc[fb][k];
        float2 lb;
        lb.x = so;
        lb.y = yp[fb][xk] - xs_s[fb][xk] * so;
        g_line[f * S_DIM + k] = lb;
        if (k < K_DIM) g_xs[f * K_DIM + k] = xs_s[fb][k];
    }
}

// ---------------------------------------------------------------------------
// Main streaming pass. Block = 64 features x 256 rows-strip.
// Tables staged in LDS with XOR swizzle: slot = key ^ (f_local>>2).
// Thread t handles features 4*(t&15)..4*(t&15)+3, so (f_local>>2) == seg id;
// within one feature row the 32 slots land in 32 distinct banks, and the
// XOR spreads concurrent data-dependent probes across banks. Same-seg lanes
// probing the same slot broadcast (no conflict).
// ---------------------------------------------------------------------------
__global__ __launch_bounds__(THREADS) void plas_main_kernel(
    const float*  __restrict__ inp,    // [B, F]
    const float*  __restrict__ g_xs,   // [F, K]
    const float2* __restrict__ g_line, // [F, S]
    float* __restrict__ out,           // [B, F]
    float* __restrict__ ssel)          // [B, F]
{
    __shared__ float lxs[TF * 32];     // swizzled: [f][k ^ swz(f)]
    __shared__ f2    lline[TF * 32];   // swizzled: [f][idx ^ swz(f)]

    const int tid = threadIdx.x;
    const int f0  = blockIdx.x * TF;

    // stage tables: 8 passes x (8 features x 32 slots)
    {
        const int fl_base = tid >> 5;      // 0..7
        const int kk      = tid & 31;
        #pragma unroll
        for (int pass = 0; pass < TF / 8; ++pass) {
            const int fl  = pass * 8 + fl_base;
            const int swz = (fl >> 2) & (SEGS - 1);
            const float2 g = g_line[(size_t)(f0 + fl) * S_DIM + kk];
            f2 gv; gv[0] = g.x; gv[1] = g.y;
            lline[fl * 32 + (kk ^ swz)] = gv;
            if (kk < K_DIM)
                lxs[fl * 32 + (kk ^ swz)] = g_xs[(size_t)(f0 + fl) * K_DIM + kk];
        }
    }
    __syncthreads();

    const int t4   = tid & (SEGS - 1);  // row-segment id == swizzle key
    const int trow = tid >> 4;          // 0..15
    const int fbse = t4 * 4;            // local feature base (4 consecutive features)
    const int swz  = t4;                // (f_local>>2) for all 4 features

    const float* xsb = &lxs[fbse * 32];
    const f2*    lnb = &lline[fbse * 32];

    const size_t stride = (size_t)ROWS_PER_PASS * F_DIM;
    size_t base = ((size_t)blockIdx.y * ROWS_PER_Y + trow) * F_DIM + f0 + fbse;

    // software-pipelined: next iteration's global load issues before the
    // current iteration's dependent LDS search chain.
    f4 x4 = __builtin_nontemporal_load((const f4*)(inp + base));

    for (int it = 0; it < ITERS; ++it) {
        f4 xn = x4;
        if (it + 1 < ITERS)
            xn = __builtin_nontemporal_load((const f4*)(inp + base + stride));

        f4 o4, s4;
        #pragma unroll
        for (int j = 0; j < 4; ++j) {
            const float* xs = xsb + j * 32;
            const float x = x4[j];
            // branchless upper_bound over 31 sorted knots (count of xs[k] <= x)
            int idx;
            idx  = (xs[15 ^ swz]        <= x) ? 16 : 0;
            idx += (xs[(idx + 7) ^ swz] <= x) ? 8 : 0;
            idx += (xs[(idx + 3) ^ swz] <= x) ? 4 : 0;
            idx += (xs[(idx + 1) ^ swz] <= x) ? 2 : 0;
            idx += (xs[idx ^ swz]       <= x) ? 1 : 0;
            const f2 lb = lnb[j * 32 + (idx ^ swz)];
            s4[j] = lb[0];
            o4[j] = fmaf(x, lb[0], lb[1]);
        }

        __builtin_nontemporal_store(o4, (f4*)(out  + base));
        __builtin_nontemporal_store(s4, (f4*)(ssel + base));
        base += stride;
        x4 = xn;
    }
}

extern "C" void kernel_launch(void* const* d_in, const int* in_sizes, int n_in,
                              void* d_out, int out_size, void* d_ws, size_t ws_size,
                              hipStream_t stream) {
    const float* inputs = (const float*)d_in[0];   // [B, F]
    const float* x_pos  = (const float*)d_in[1];   // [F, K]
    const float* slope  = (const float*)d_in[2];   // [F, S]
    const float* y_bias = (const float*)d_in[3];   // [F, 1]

    float* out  = (float*)d_out;                   // outputs [B,F]
    float* ssel = (float*)d_out + (size_t)B_DIM * F_DIM;  // slope_sel [B,F]

    // workspace layout: line table first (8B aligned), then sorted knots
    float2* g_line = (float2*)d_ws;                         // F*S float2 = 128 KiB
    float*  g_xs   = (float*)d_ws + (size_t)F_DIM * S_DIM * 2;  // F*K floats

    plas_setup_kernel<<<F_DIM / 8, 256, 0, stream>>>(x_pos, slope, y_bias, g_xs, g_line);

    dim3 grid(GRID_X, GRID_Y);
    plas_main_kernel<<<grid, THREADS, 0, stream>>>(inputs, g_xs, g_line, out, ssel);
}